// Round 3
// baseline (345.466 us; speedup 1.0000x reference)
//
#include <hip/hip_runtime.h>

// Problem constants (from reference)
#define BS 65536
#define NE 512
#define D  768
#define D4 192                     // D / 4 (float4 per row); 192 = 3 * 64 lanes
#define ROWS_PER_WAVE 4
#define WAVES_PER_BLOCK 4
#define ROWS_PER_BLOCK 16          // 4 waves * 4 rows each
#define NBLK (BS / ROWS_PER_BLOCK) // 4096 blocks
#define NPART (NBLK * WAVES_PER_BLOCK) // 16384 per-wave partials (128 KB ws)

// Native clang vector type — required by __builtin_nontemporal_store
// (HIP's float4 is a struct wrapper that the builtin rejects).
typedef float floatx4 __attribute__((ext_vector_type(4)));

// One wave (64 lanes) owns FOUR whole rows, fully straight-line:
//   1 s_load_dwordx4 of categories (scalar pipe, overlaps everything)
//   12 input float4 loads + 12 gather float4 loads in flight (24 KB/wave MLP)
//   12 nontemporal float4 stores (write-once stream, don't pollute L2/L3)
//   NO __syncthreads / LDS tail — each wave writes its own loss partial.
__global__ __launch_bounds__(256) void vq_main(
    const float4* __restrict__ inputs,
    const int*    __restrict__ categories,
    const float4* __restrict__ codebook,
    float4*       __restrict__ out,
    double*       __restrict__ partials)
{
    const int lane = threadIdx.x & 63;
    const int wave = threadIdx.x >> 6;
    const int row0 = blockIdx.x * ROWS_PER_BLOCK + wave * ROWS_PER_WAVE;
    // row0 is wave-uniform; readfirstlane lets the compiler emit scalar loads
    const int r0 = __builtin_amdgcn_readfirstlane(row0);

    // 4 contiguous wave-uniform category reads -> one s_load_dwordx4
    int cat[ROWS_PER_WAVE];
    #pragma unroll
    for (int j = 0; j < ROWS_PER_WAVE; ++j)
        cat[j] = categories[r0 + j];

    // 12 independent input loads — no dependency on categories
    const float4* ip = inputs + (size_t)row0 * D4 + lane;
    float4 x[12];
    #pragma unroll
    for (int j = 0; j < 12; ++j)
        x[j] = ip[j * 64];

    // 12 gather loads (codebook is 1.5 MB — L2-resident on every XCD)
    float4 q[12];
    #pragma unroll
    for (int j = 0; j < ROWS_PER_WAVE; ++j) {
        const float4* cb = codebook + (size_t)cat[j] * D4 + lane;
        #pragma unroll
        for (int k = 0; k < 3; ++k)
            q[j * 3 + k] = cb[k * 64];
    }

    // quantized_st forward value == quantized: out is just the gathered rows.
    // Nontemporal: written once, never read — keep L2 for codebook/inputs.
    floatx4* op = (floatx4*)(out + (size_t)row0 * D4 + lane);
    #pragma unroll
    for (int j = 0; j < 12; ++j)
        __builtin_nontemporal_store(
            (floatx4){q[j].x, q[j].y, q[j].z, q[j].w}, op + j * 64);

    float acc = 0.0f;
    #pragma unroll
    for (int j = 0; j < 12; ++j) {
        float dx;
        dx = q[j].x - x[j].x; acc += dx * dx;
        dx = q[j].y - x[j].y; acc += dx * dx;
        dx = q[j].z - x[j].z; acc += dx * dx;
        dx = q[j].w - x[j].w; acc += dx * dx;
    }

    // Wave (64-lane) shuffle reduction; one partial per wave, no barrier.
    #pragma unroll
    for (int off = 32; off > 0; off >>= 1)
        acc += __shfl_down(acc, off, 64);

    if (lane == 0)
        partials[blockIdx.x * WAVES_PER_BLOCK + wave] = (double)acc;
}

// Finalize: reduce 16384 per-wave partials (written by vq_main, visible across
// the kernel boundary on the same stream) -> loss scalar at out[BS*D].
// loss = (CODEBOOK_COST + COMMITMENT_COST) * mean(diff^2) = 1.25 * sum / (BS*D)
__global__ void vq_finalize(const double* __restrict__ partials,
                            float* __restrict__ loss_out)
{
    const int t = threadIdx.x;
    double s = 0.0;
    #pragma unroll
    for (int k = 0; k < NPART / 256; ++k)      // 64 coalesced loads/thread
        s += partials[t + (k << 8)];

    #pragma unroll
    for (int off = 32; off > 0; off >>= 1)
        s += __shfl_down(s, off, 64);

    __shared__ double wsum[4];
    const int lane = t & 63, wave = t >> 6;
    if (lane == 0) wsum[wave] = s;
    __syncthreads();

    if (t == 0) {
        const double tot = wsum[0] + wsum[1] + wsum[2] + wsum[3];
        *loss_out = (float)(tot * (1.25 / ((double)BS * (double)D)));
    }
}

extern "C" void kernel_launch(void* const* d_in, const int* in_sizes, int n_in,
                              void* d_out, int out_size, void* d_ws, size_t ws_size,
                              hipStream_t stream) {
    const float4* inputs     = (const float4*)d_in[0];
    const int*    categories = (const int*)  d_in[1];  // jnp.int64 canonicalizes to int32
    const float4* codebook   = (const float4*)d_in[2];
    float*        out        = (float*)d_out;
    double*       partials   = (double*)d_ws;          // 16384 * 8 B = 128 KB of workspace

    // Every partial slot is overwritten by vq_main before vq_finalize reads it,
    // so no memset of the poisoned workspace is needed.
    vq_main<<<NBLK, 256, 0, stream>>>(inputs, categories, codebook,
                                      (float4*)out, partials);
    vq_finalize<<<1, 256, 0, stream>>>(partials, out + (size_t)BS * D);
}

// Round 4
// 336.923 us; speedup vs baseline: 1.0254x; 1.0254x over previous
//
#include <hip/hip_runtime.h>

// Problem constants (from reference)
#define BS 65536
#define NE 512
#define D  768
#define D4 192                     // D / 4 (float4 per row); 192 = 3 * 64 lanes
#define ROWS_PER_WAVE 2
#define WAVES_PER_BLOCK 4
#define ROWS_PER_BLOCK 8           // 4 waves * 2 rows each
#define NBLK (BS / ROWS_PER_BLOCK) // 8192 blocks (best geometry so far, R2)
#define NPART (NBLK * WAVES_PER_BLOCK) // 32768 float partials = 128 KB ws

// One wave (64 lanes) owns TWO whole rows, fully straight-line:
//   2 scalar category loads (via readfirstlane -> s_load, overlaps VMEM)
//   6 input float4 loads + 6 gather float4 loads in flight (12 KB/wave MLP)
//   6 PLAIN float4 stores  <-- experiment: NT hint removed (suspected slow
//                              write path; harness fill hits 6.7 TB/s with
//                              plain stores)
//   NO __syncthreads / LDS tail — each wave writes its own loss partial.
__global__ __launch_bounds__(256) void vq_main(
    const float4* __restrict__ inputs,
    const int*    __restrict__ categories,
    const float4* __restrict__ codebook,
    float4*       __restrict__ out,
    float*        __restrict__ partials)
{
    const int lane = threadIdx.x & 63;
    const int wave = threadIdx.x >> 6;
    const int row0 = blockIdx.x * ROWS_PER_BLOCK + wave * ROWS_PER_WAVE;
    // row0 is wave-uniform; readfirstlane lets the compiler emit scalar loads
    const int r0 = __builtin_amdgcn_readfirstlane(row0);

    // 2 contiguous wave-uniform category reads -> one s_load_dwordx2
    const int c0 = categories[r0];
    const int c1 = categories[r0 + 1];

    // 6 independent input loads — no dependency on categories
    const float4* ip = inputs + (size_t)row0 * D4 + lane;
    const float4 x00 = ip[0],   x01 = ip[64],  x02 = ip[128];
    const float4 x10 = ip[192], x11 = ip[256], x12 = ip[320];

    // 6 gather loads (codebook is 1.5 MB — L2-resident on every XCD)
    const float4* cb0 = codebook + (size_t)c0 * D4 + lane;
    const float4* cb1 = codebook + (size_t)c1 * D4 + lane;
    const float4 q00 = cb0[0], q01 = cb0[64], q02 = cb0[128];
    const float4 q10 = cb1[0], q11 = cb1[64], q12 = cb1[128];

    // quantized_st forward value == quantized: out is just the gathered rows.
    float4* op = out + (size_t)row0 * D4 + lane;
    op[0]   = q00;  op[64]  = q01;  op[128] = q02;
    op[192] = q10;  op[256] = q11;  op[320] = q12;

    float acc = 0.0f;
    {
        float dx;
        dx = q00.x - x00.x; acc += dx * dx;  dx = q00.y - x00.y; acc += dx * dx;
        dx = q00.z - x00.z; acc += dx * dx;  dx = q00.w - x00.w; acc += dx * dx;
        dx = q01.x - x01.x; acc += dx * dx;  dx = q01.y - x01.y; acc += dx * dx;
        dx = q01.z - x01.z; acc += dx * dx;  dx = q01.w - x01.w; acc += dx * dx;
        dx = q02.x - x02.x; acc += dx * dx;  dx = q02.y - x02.y; acc += dx * dx;
        dx = q02.z - x02.z; acc += dx * dx;  dx = q02.w - x02.w; acc += dx * dx;
        dx = q10.x - x10.x; acc += dx * dx;  dx = q10.y - x10.y; acc += dx * dx;
        dx = q10.z - x10.z; acc += dx * dx;  dx = q10.w - x10.w; acc += dx * dx;
        dx = q11.x - x11.x; acc += dx * dx;  dx = q11.y - x11.y; acc += dx * dx;
        dx = q11.z - x11.z; acc += dx * dx;  dx = q11.w - x11.w; acc += dx * dx;
        dx = q12.x - x12.x; acc += dx * dx;  dx = q12.y - x12.y; acc += dx * dx;
        dx = q12.z - x12.z; acc += dx * dx;  dx = q12.w - x12.w; acc += dx * dx;
    }

    // Wave (64-lane) shuffle reduction; one partial per wave, no barrier.
    #pragma unroll
    for (int off = 32; off > 0; off >>= 1)
        acc += __shfl_down(acc, off, 64);

    if (lane == 0)
        partials[blockIdx.x * WAVES_PER_BLOCK + wave] = acc;
}

// Finalize: reduce 32768 per-wave partials (written by vq_main, visible across
// the kernel boundary on the same stream) -> loss scalar at out[BS*D].
// loss = (CODEBOOK_COST + COMMITMENT_COST) * mean(diff^2) = 1.25 * sum / (BS*D)
__global__ __launch_bounds__(1024) void vq_finalize(
    const float* __restrict__ partials,
    float*       __restrict__ loss_out)
{
    const int t = threadIdx.x;
    double s = 0.0;
    #pragma unroll
    for (int k = 0; k < NPART / 1024; ++k)     // 32 coalesced loads/thread
        s += (double)partials[t + (k << 10)];

    #pragma unroll
    for (int off = 32; off > 0; off >>= 1)
        s += __shfl_down(s, off, 64);

    __shared__ double wsum[16];
    const int lane = t & 63, wave = t >> 6;
    if (lane == 0) wsum[wave] = s;
    __syncthreads();

    if (t == 0) {
        double tot = 0.0;
        #pragma unroll
        for (int w = 0; w < 16; ++w) tot += wsum[w];
        *loss_out = (float)(tot * (1.25 / ((double)BS * (double)D)));
    }
}

extern "C" void kernel_launch(void* const* d_in, const int* in_sizes, int n_in,
                              void* d_out, int out_size, void* d_ws, size_t ws_size,
                              hipStream_t stream) {
    const float4* inputs     = (const float4*)d_in[0];
    const int*    categories = (const int*)  d_in[1];  // jnp.int64 canonicalizes to int32
    const float4* codebook   = (const float4*)d_in[2];
    float*        out        = (float*)d_out;
    float*        partials   = (float*)d_ws;           // 32768 * 4 B = 128 KB of workspace

    // Every partial slot is overwritten by vq_main before vq_finalize reads it,
    // so no memset of the poisoned workspace is needed.
    vq_main<<<NBLK, 256, 0, stream>>>(inputs, categories, codebook,
                                      (float4*)out, partials);
    vq_finalize<<<1, 1024, 0, stream>>>(partials, out + (size_t)BS * D);
}